// Round 1
// baseline (377.727 us; speedup 1.0000x reference)
//
#include <hip/hip_runtime.h>

#define NMOL 16
#define NAT  512
#define NK   27

// Bit-exact float32 constants matching the numpy reference on host:
//   inv_cell diagonal = 1/20 correctly rounded = 0.05f (0x3D4CCCCD)
//   mask: dist<5.0 with correctly-rounded sqrt  <=>  ss < pred(25.0f) = 0x41C7FFFF
#define SSMAX 24.999998092651367f

__device__ __forceinline__ float wrap1(float v) {
    // proj = rn(v*0.05f); coords in [0,20) => proj<1 => woff=0, frac=proj
    // wrapped = rn(frac*20)
    return __fmul_rn(__fmul_rn(v, 0.05f), 20.0f);
}

// Candidate (unique possible) image per component + exact-mask squared distance test.
__device__ __forceinline__ bool probe(float dx, float dy, float dz,
                                      int& ox, int& oy, int& oz,
                                      float& cx, float& cy, float& cz) {
    ox = (dx > 15.0f) ? -1 : ((dx < -15.0f) ? 1 : 0);
    oy = (dy > 15.0f) ? -1 : ((dy < -15.0f) ? 1 : 0);
    oz = (dz > 15.0f) ? -1 : ((dz < -15.0f) ? 1 : 0);
    cx = 20.0f * (float)ox;
    cy = 20.0f * (float)oy;
    cz = 20.0f * (float)oz;
    float ax = __fadd_rn(dx, cx);
    float ay = __fadd_rn(dy, cy);
    float az = __fadd_rn(dz, cz);
    float ss = __fadd_rn(__fadd_rn(__fmul_rn(ax, ax), __fmul_rn(ay, ay)),
                         __fmul_rn(az, az));
    return ss < SSMAX;
}

// ---------------- Pass A: count hits per (m, k, i) ----------------
__global__ __launch_bounds__(256) void pass_count(const float* __restrict__ coords,
                                                  int* __restrict__ cnt) {
    __shared__ float w4[NAT * 4];        // wrapped coords, padded to float4
    __shared__ int   hist[256 * NK];
    const int blk = blockIdx.x;
    const int m   = blk >> 1;
    const int i0  = (blk & 1) * 256;
    const int t   = threadIdx.x;

    const float* cm = coords + (size_t)m * NAT * 3;
    for (int q = t; q < NAT * 3; q += 256) {
        int a = q / 3, c = q - a * 3;
        w4[a * 4 + c] = wrap1(cm[q]);
    }
    for (int a = t; a < NAT; a += 256) w4[a * 4 + 3] = 0.0f;

    int* h = hist + t * NK;
    #pragma unroll
    for (int k = 0; k < NK; ++k) h[k] = 0;
    __syncthreads();

    const int i = i0 + t;
    const float wx = w4[i * 4 + 0];
    const float wy = w4[i * 4 + 1];
    const float wz = w4[i * 4 + 2];
    const float4* w4p = reinterpret_cast<const float4*>(w4);

    for (int j = 0; j < NAT; ++j) {
        float4 wj = w4p[j];                       // wave-broadcast ds_read_b128
        float dx = __fsub_rn(wx, wj.x);
        float dy = __fsub_rn(wy, wj.y);
        float dz = __fsub_rn(wz, wj.z);
        int ox, oy, oz; float cx, cy, cz;
        bool hit = probe(dx, dy, dz, ox, oy, oz, cx, cy, cz);
        if (hit && j != i) {
            int k = (ox + 1) * 9 + (oy + 1) * 3 + (oz + 1);
            h[k]++;
        }
    }

    #pragma unroll
    for (int k = 0; k < NK; ++k)
        cnt[(m * NK + k) * NAT + i] = h[k];
}

// ---------------- Pass B1: per-chunk (512-wide) exclusive scan, in place ----------------
__global__ __launch_bounds__(512) void scan_chunk(int* __restrict__ cnt,
                                                  int* __restrict__ sums) {
    __shared__ int buf[512];
    const int c = blockIdx.x;
    const int t = threadIdx.x;
    const int idx = c * 512 + t;
    buf[t] = cnt[idx];
    __syncthreads();
    for (int d = 1; d < 512; d <<= 1) {
        int v = (t >= d) ? buf[t - d] : 0;
        __syncthreads();
        buf[t] += v;
        __syncthreads();
    }
    cnt[idx] = (t == 0) ? 0 : buf[t - 1];
    if (t == 511) sums[c] = buf[511];
}

// ---------------- Pass B2: exclusive scan of 432 chunk sums ----------------
__global__ __launch_bounds__(512) void scan_sums(int* __restrict__ sums) {
    __shared__ int buf[512];
    const int t = threadIdx.x;
    buf[t] = (t < NMOL * NK) ? sums[t] : 0;
    __syncthreads();
    for (int d = 1; d < 512; d <<= 1) {
        int v = (t >= d) ? buf[t - d] : 0;
        __syncthreads();
        buf[t] += v;
        __syncthreads();
    }
    if (t < NMOL * NK) sums[t] = (t == 0) ? 0 : buf[t - 1];
}

// ---------------- Pass C: recompute selection, emit outputs in exact order ----------------
__global__ __launch_bounds__(256) void pass_emit(const float* __restrict__ coords,
                                                 const int* __restrict__ cnt,
                                                 const int* __restrict__ sums,
                                                 float* __restrict__ out, int P) {
    __shared__ float w4[NAT * 4];   // wrapped (selection)
    __shared__ float r4[NAT * 4];   // raw (output paircoord/dist)
    __shared__ int   cur[256 * NK];
    const int blk = blockIdx.x;
    const int m   = blk >> 1;
    const int i0  = (blk & 1) * 256;
    const int t   = threadIdx.x;

    const float* cm = coords + (size_t)m * NAT * 3;
    for (int q = t; q < NAT * 3; q += 256) {
        int a = q / 3, c = q - a * 3;
        float v = cm[q];
        r4[a * 4 + c] = v;
        w4[a * 4 + c] = wrap1(v);
    }
    for (int a = t; a < NAT; a += 256) { w4[a * 4 + 3] = 0.0f; r4[a * 4 + 3] = 0.0f; }

    const int i = i0 + t;
    int* cu = cur + t * NK;
    #pragma unroll
    for (int k = 0; k < NK; ++k)
        cu[k] = cnt[(m * NK + k) * NAT + i] + sums[m * NK + k];
    __syncthreads();

    const float wx = w4[i * 4 + 0];
    const float wy = w4[i * 4 + 1];
    const float wz = w4[i * 4 + 2];
    const float rx = r4[i * 4 + 0];
    const float ry = r4[i * 4 + 1];
    const float rz = r4[i * 4 + 2];
    const float4* w4p = reinterpret_cast<const float4*>(w4);
    const float4* r4p = reinterpret_cast<const float4*>(r4);
    const int pf = m * NAT + i;

    for (int j = 0; j < NAT; ++j) {
        float4 wj = w4p[j];
        float dx = __fsub_rn(wx, wj.x);
        float dy = __fsub_rn(wy, wj.y);
        float dz = __fsub_rn(wz, wj.z);
        int ox, oy, oz; float cx, cy, cz;
        bool hit = probe(dx, dy, dz, ox, oy, oz, cx, cy, cz);
        if (hit && j != i) {
            int k = (ox + 1) * 9 + (oy + 1) * 3 + (oz + 1);
            int p = cu[k]++;
            if (p < P) {
                float4 rj = r4p[j];
                // paircoord = coord_i - coord_j + offsets@cell (offsets*20 exact)
                float px = __fadd_rn(__fsub_rn(rx, rj.x), cx);
                float py = __fadd_rn(__fsub_rn(ry, rj.y), cy);
                float pz = __fadd_rn(__fsub_rn(rz, rj.z), cz);
                float ss = __fadd_rn(__fadd_rn(__fmul_rn(px, px), __fmul_rn(py, py)),
                                     __fmul_rn(pz, pz));
                out[p]                 = __fsqrt_rn(ss);        // distflat2
                out[P + p]             = (float)pf;             // pair_first
                out[2 * P + p]         = (float)(m * NAT + j);  // pair_second
                out[3 * P + 3 * p + 0] = px;                    // paircoord
                out[3 * P + 3 * p + 1] = py;
                out[3 * P + 3 * p + 2] = pz;
                out[6 * P + 3 * p + 0] = (float)ox;             // offsets
                out[6 * P + 3 * p + 1] = (float)oy;
                out[6 * P + 3 * p + 2] = (float)oz;
                out[9 * P + p]         = (float)k;              // offset_index (n_images=1 -> ==k)
            }
        }
    }
}

extern "C" void kernel_launch(void* const* d_in, const int* in_sizes, int n_in,
                              void* d_out, int out_size, void* d_ws, size_t ws_size,
                              hipStream_t stream) {
    const float* coords = (const float*)d_in[0];
    int* cnt  = (int*)d_ws;               // NMOL*NK*NAT ints
    int* sums = cnt + NMOL * NK * NAT;    // NMOL*NK ints
    float* out = (float*)d_out;
    const int P = out_size / 10;

    hipLaunchKernelGGL(pass_count, dim3(NMOL * 2), dim3(256), 0, stream, coords, cnt);
    hipLaunchKernelGGL(scan_chunk, dim3(NMOL * NK), dim3(512), 0, stream, cnt, sums);
    hipLaunchKernelGGL(scan_sums, dim3(1), dim3(512), 0, stream, sums);
    hipLaunchKernelGGL(pass_emit, dim3(NMOL * 2), dim3(256), 0, stream, coords, cnt, sums, out, P);
}

// Round 2
// 97.597 us; speedup vs baseline: 3.8703x; 3.8703x over previous
//
#include <hip/hip_runtime.h>

#define NMOL 16
#define NAT  512
#define NK   27

// Bit-exact float32 constants matching the numpy reference on host:
//   inv_cell diagonal = 1/20 correctly rounded = 0.05f (0x3D4CCCCD)
//   mask: dist<5.0 with correctly-rounded sqrt  <=>  ss < pred(25.0f) = 0x41C7FFFF
#define SSMAX 24.999998092651367f

__device__ __forceinline__ float wrap1(float v) {
    // proj = rn(v*0.05f); coords in [0,20) => proj<1 => woff=0, frac=proj
    // wrapped = rn(frac*20)
    return __fmul_rn(__fmul_rn(v, 0.05f), 20.0f);
}

// Candidate (unique possible) image per component + exact-mask squared distance test.
__device__ __forceinline__ bool probe(float dx, float dy, float dz,
                                      int& ox, int& oy, int& oz,
                                      float& cx, float& cy, float& cz) {
    ox = (dx > 15.0f) ? -1 : ((dx < -15.0f) ? 1 : 0);
    oy = (dy > 15.0f) ? -1 : ((dy < -15.0f) ? 1 : 0);
    oz = (dz > 15.0f) ? -1 : ((dz < -15.0f) ? 1 : 0);
    cx = 20.0f * (float)ox;
    cy = 20.0f * (float)oy;
    cz = 20.0f * (float)oz;
    float ax = __fadd_rn(dx, cx);
    float ay = __fadd_rn(dy, cy);
    float az = __fadd_rn(dz, cz);
    float ss = __fadd_rn(__fadd_rn(__fmul_rn(ax, ax), __fmul_rn(ay, ay)),
                         __fmul_rn(az, az));
    return ss < SSMAX;
}

// ---------------- Pass A: count hits per (m, k, i) ----------------
// 1 wave per atom i, lanes cover j. Grid = NMOL * NAT/4, block = 256 (4 waves).
__global__ __launch_bounds__(256) void pass_count(const float* __restrict__ coords,
                                                  int* __restrict__ cnt) {
    __shared__ float w4[NAT * 4];        // wrapped coords, padded to float4
    __shared__ int   cur[4][NK];
    const int blk = blockIdx.x;
    const int m   = blk >> 7;            // 128 blocks per molecule
    const int ig  = blk & 127;
    const int t   = threadIdx.x;
    const int w   = t >> 6;              // wave id 0..3
    const int lane = t & 63;
    const int i   = ig * 4 + w;

    const float* cm = coords + (size_t)m * NAT * 3;
    for (int q = t; q < NAT * 3; q += 256) {
        int a = q / 3, c = q - a * 3;
        w4[a * 4 + c] = wrap1(cm[q]);
    }
    if (t < 4 * NK) cur[t / NK][t % NK] = 0;
    __syncthreads();

    const float wx = w4[i * 4 + 0];
    const float wy = w4[i * 4 + 1];
    const float wz = w4[i * 4 + 2];
    const float4* w4p = reinterpret_cast<const float4*>(w4);

    #pragma unroll
    for (int it = 0; it < NAT / 64; ++it) {
        const int j = it * 64 + lane;
        float4 wj = w4p[j];
        float dx = __fsub_rn(wx, wj.x);
        float dy = __fsub_rn(wy, wj.y);
        float dz = __fsub_rn(wz, wj.z);
        int ox, oy, oz; float cx, cy, cz;
        bool hit = probe(dx, dy, dz, ox, oy, oz, cx, cy, cz) && (j != i);
        if (hit) {
            int k = (ox + 1) * 9 + (oy + 1) * 3 + (oz + 1);
            atomicAdd(&cur[w][k], 1);
        }
    }
    __syncthreads();

    if (t < 4 * NK) {
        int ww = t / NK, k = t % NK;
        cnt[(m * NK + k) * NAT + (ig * 4 + ww)] = cur[ww][k];
    }
}

// ---------------- Pass B1: per-chunk (512-wide) exclusive scan, in place ----------------
__global__ __launch_bounds__(512) void scan_chunk(int* __restrict__ cnt,
                                                  int* __restrict__ sums) {
    __shared__ int buf[512];
    const int c = blockIdx.x;
    const int t = threadIdx.x;
    const int idx = c * 512 + t;
    buf[t] = cnt[idx];
    __syncthreads();
    for (int d = 1; d < 512; d <<= 1) {
        int v = (t >= d) ? buf[t - d] : 0;
        __syncthreads();
        buf[t] += v;
        __syncthreads();
    }
    cnt[idx] = (t == 0) ? 0 : buf[t - 1];
    if (t == 511) sums[c] = buf[511];
}

// ---------------- Pass B2: exclusive scan of 432 chunk sums ----------------
__global__ __launch_bounds__(512) void scan_sums(int* __restrict__ sums) {
    __shared__ int buf[512];
    const int t = threadIdx.x;
    buf[t] = (t < NMOL * NK) ? sums[t] : 0;
    __syncthreads();
    for (int d = 1; d < 512; d <<= 1) {
        int v = (t >= d) ? buf[t - d] : 0;
        __syncthreads();
        buf[t] += v;
        __syncthreads();
    }
    if (t < NMOL * NK) sums[t] = (t == 0) ? 0 : buf[t - 1];
}

// ---------------- Pass C: recompute selection, emit outputs in exact order ----------------
// 1 wave per atom i, lanes cover j. Ordered ranks within (i,k) via ballot
// match-any over the 5-bit k + leader LDS fetch-and-add + shfl broadcast.
// j-iterations run in ascending-j order, so per-(i,k) bases accumulate in
// exactly the serial (m,k,i,j) order of the reference.
__global__ __launch_bounds__(256) void pass_emit(const float* __restrict__ coords,
                                                 const int* __restrict__ cnt,
                                                 const int* __restrict__ sums,
                                                 float* __restrict__ out, int P) {
    __shared__ float w4[NAT * 4];   // wrapped (selection)
    __shared__ float r4[NAT * 4];   // raw (output paircoord/dist)
    __shared__ int   cur[4][NK];    // running output cursor per (wave's i, k)
    const int blk = blockIdx.x;
    const int m   = blk >> 7;
    const int ig  = blk & 127;
    const int t   = threadIdx.x;
    const int w   = t >> 6;
    const int lane = t & 63;
    const int i   = ig * 4 + w;

    const float* cm = coords + (size_t)m * NAT * 3;
    for (int q = t; q < NAT * 3; q += 256) {
        int a = q / 3, c = q - a * 3;
        float v = cm[q];
        r4[a * 4 + c] = v;
        w4[a * 4 + c] = wrap1(v);
    }
    if (t < 4 * NK) {
        int ww = t / NK, k = t % NK;
        cur[ww][k] = cnt[(m * NK + k) * NAT + (ig * 4 + ww)] + sums[m * NK + k];
    }
    __syncthreads();

    const float wx = w4[i * 4 + 0];
    const float wy = w4[i * 4 + 1];
    const float wz = w4[i * 4 + 2];
    const float rx = r4[i * 4 + 0];
    const float ry = r4[i * 4 + 1];
    const float rz = r4[i * 4 + 2];
    const float4* w4p = reinterpret_cast<const float4*>(w4);
    const float4* r4p = reinterpret_cast<const float4*>(r4);
    const int pf = m * NAT + i;
    const unsigned long long ltmask =
        (lane == 0) ? 0ull : (~0ull >> (64 - lane));

    #pragma unroll
    for (int it = 0; it < NAT / 64; ++it) {
        const int j = it * 64 + lane;
        float4 wj = w4p[j];
        float dx = __fsub_rn(wx, wj.x);
        float dy = __fsub_rn(wy, wj.y);
        float dz = __fsub_rn(wz, wj.z);
        int ox, oy, oz; float cx, cy, cz;
        bool hit = probe(dx, dy, dz, ox, oy, oz, cx, cy, cz) && (j != i);
        int kk = hit ? ((ox + 1) * 9 + (oy + 1) * 3 + (oz + 1)) : 0;

        // match-any over 5-bit kk among hitting lanes
        unsigned long long grp = __ballot(hit);
        #pragma unroll
        for (int b = 0; b < 5; ++b) {
            unsigned long long bm = __ballot((kk >> b) & 1);
            grp &= ((kk >> b) & 1) ? bm : ~bm;
        }
        int leader = hit ? (__ffsll((unsigned long long)grp) - 1) : 0;
        int cntg   = __popcll(grp);
        int rank   = __popcll(grp & ltmask);

        int base = 0;
        if (hit && lane == leader)
            base = atomicAdd(&cur[w][kk], cntg);   // ds_add_rtn
        base = __shfl(base, leader, 64);           // broadcast from group leader

        if (hit) {
            int p = base + rank;
            if (p < P) {
                float4 rj = r4p[j];
                float px = __fadd_rn(__fsub_rn(rx, rj.x), cx);
                float py = __fadd_rn(__fsub_rn(ry, rj.y), cy);
                float pz = __fadd_rn(__fsub_rn(rz, rj.z), cz);
                float ss = __fadd_rn(__fadd_rn(__fmul_rn(px, px), __fmul_rn(py, py)),
                                     __fmul_rn(pz, pz));
                out[p]                 = __fsqrt_rn(ss);        // distflat2
                out[P + p]             = (float)pf;             // pair_first
                out[2 * P + p]         = (float)(m * NAT + j);  // pair_second
                out[3 * P + 3 * p + 0] = px;                    // paircoord
                out[3 * P + 3 * p + 1] = py;
                out[3 * P + 3 * p + 2] = pz;
                out[6 * P + 3 * p + 0] = (float)ox;             // offsets
                out[6 * P + 3 * p + 1] = (float)oy;
                out[6 * P + 3 * p + 2] = (float)oz;
                out[9 * P + p]         = (float)kk;             // offset_index (n_images=1)
            }
        }
    }
}

extern "C" void kernel_launch(void* const* d_in, const int* in_sizes, int n_in,
                              void* d_out, int out_size, void* d_ws, size_t ws_size,
                              hipStream_t stream) {
    const float* coords = (const float*)d_in[0];
    int* cnt  = (int*)d_ws;               // NMOL*NK*NAT ints
    int* sums = cnt + NMOL * NK * NAT;    // NMOL*NK ints
    float* out = (float*)d_out;
    const int P = out_size / 10;

    hipLaunchKernelGGL(pass_count, dim3(NMOL * NAT / 4), dim3(256), 0, stream, coords, cnt);
    hipLaunchKernelGGL(scan_chunk, dim3(NMOL * NK), dim3(512), 0, stream, cnt, sums);
    hipLaunchKernelGGL(scan_sums, dim3(1), dim3(512), 0, stream, sums);
    hipLaunchKernelGGL(pass_emit, dim3(NMOL * NAT / 4), dim3(256), 0, stream,
                       coords, cnt, sums, out, P);
}

// Round 3
// 96.124 us; speedup vs baseline: 3.9296x; 1.0153x over previous
//
#include <hip/hip_runtime.h>

#define NMOL 16
#define NAT  512
#define NK   27

// Bit-exact float32 constants matching the numpy reference on host:
//   inv_cell diagonal = 1/20 correctly rounded = 0.05f (0x3D4CCCCD)
//   mask: dist<5.0 with correctly-rounded sqrt  <=>  ss < pred(25.0f) = 0x41C7FFFF
#define SSMAX 24.999998092651367f

__device__ __forceinline__ float wrap1(float v) {
    // proj = rn(v*0.05f); coords in [0,20) => proj<1 => woff=0, frac=proj
    // wrapped = rn(frac*20)
    return __fmul_rn(__fmul_rn(v, 0.05f), 20.0f);
}

// Candidate (unique possible) image per component + exact-mask squared distance test.
__device__ __forceinline__ bool probe(float dx, float dy, float dz,
                                      int& ox, int& oy, int& oz,
                                      float& cx, float& cy, float& cz) {
    ox = (dx > 15.0f) ? -1 : ((dx < -15.0f) ? 1 : 0);
    oy = (dy > 15.0f) ? -1 : ((dy < -15.0f) ? 1 : 0);
    oz = (dz > 15.0f) ? -1 : ((dz < -15.0f) ? 1 : 0);
    cx = 20.0f * (float)ox;
    cy = 20.0f * (float)oy;
    cz = 20.0f * (float)oz;
    float ax = __fadd_rn(dx, cx);
    float ay = __fadd_rn(dy, cy);
    float az = __fadd_rn(dz, cz);
    float ss = __fadd_rn(__fadd_rn(__fmul_rn(ax, ax), __fmul_rn(ay, ay)),
                         __fmul_rn(az, az));
    return ss < SSMAX;
}

// ---------------- Pass A: count hits per (m, k, i) ----------------
// 1 wave per atom i, lanes cover j. launch_bounds(256,8): cap VGPR at 64 so
// 8 blocks/CU co-reside -> the 2048-block grid runs in ONE round (no tail).
__global__ __launch_bounds__(256, 8) void pass_count(const float* __restrict__ coords,
                                                     int* __restrict__ cnt) {
    __shared__ float w4[NAT * 4];        // wrapped coords, padded to float4
    __shared__ int   cur[4][NK];
    const int blk = blockIdx.x;
    const int m   = blk >> 7;            // 128 blocks per molecule
    const int ig  = blk & 127;
    const int t   = threadIdx.x;
    const int w   = t >> 6;              // wave id 0..3
    const int lane = t & 63;
    const int i   = ig * 4 + w;

    const float* cm = coords + (size_t)m * NAT * 3;
    for (int q = t; q < NAT * 3; q += 256) {
        int a = q / 3, c = q - a * 3;
        w4[a * 4 + c] = wrap1(cm[q]);
    }
    if (t < 4 * NK) cur[t / NK][t % NK] = 0;
    __syncthreads();

    const float wx = w4[i * 4 + 0];
    const float wy = w4[i * 4 + 1];
    const float wz = w4[i * 4 + 2];
    const float4* w4p = reinterpret_cast<const float4*>(w4);

    #pragma unroll
    for (int it = 0; it < NAT / 64; ++it) {
        const int j = it * 64 + lane;
        float4 wj = w4p[j];
        float dx = __fsub_rn(wx, wj.x);
        float dy = __fsub_rn(wy, wj.y);
        float dz = __fsub_rn(wz, wj.z);
        int ox, oy, oz; float cx, cy, cz;
        bool hit = probe(dx, dy, dz, ox, oy, oz, cx, cy, cz) && (j != i);
        if (hit) {
            int k = (ox + 1) * 9 + (oy + 1) * 3 + (oz + 1);
            atomicAdd(&cur[w][k], 1);
        }
    }
    __syncthreads();

    if (t < 4 * NK) {
        int ww = t / NK, k = t % NK;
        cnt[(m * NK + k) * NAT + (ig * 4 + ww)] = cur[ww][k];
    }
}

// ---------------- Pass B: per-chunk (512-wide) exclusive scan, in place ----------------
// Writes RAW chunk totals to sums[c]; the global scan over the 432 totals is
// done redundantly per-block inside pass_emit (removes the scan_sums launch).
__global__ __launch_bounds__(512) void scan_chunk(int* __restrict__ cnt,
                                                  int* __restrict__ sums) {
    __shared__ int buf[512];
    const int c = blockIdx.x;
    const int t = threadIdx.x;
    const int idx = c * 512 + t;
    buf[t] = cnt[idx];
    __syncthreads();
    for (int d = 1; d < 512; d <<= 1) {
        int v = (t >= d) ? buf[t - d] : 0;
        __syncthreads();
        buf[t] += v;
        __syncthreads();
    }
    cnt[idx] = (t == 0) ? 0 : buf[t - 1];
    if (t == 511) sums[c] = buf[511];          // raw total, NOT scanned
}

// ---------------- Pass C: recompute selection, emit outputs in exact order ----------------
// 1 wave per atom i, lanes cover j. Ordered ranks within (i,k) via ballot
// match-any over the 5-bit k + leader LDS fetch-and-add + shfl broadcast.
// Block self-scans the 432 chunk totals in LDS for the global (m,k) base.
__global__ __launch_bounds__(256, 8) void pass_emit(const float* __restrict__ coords,
                                                    const int* __restrict__ cnt,
                                                    const int* __restrict__ sums,
                                                    float* __restrict__ out, int P) {
    __shared__ float w4[NAT * 4];   // wrapped (selection)
    __shared__ float r4[NAT * 4];   // raw (output paircoord/dist)
    __shared__ int   sbuf[512];     // chunk-total scan buffer (432 real + pad)
    __shared__ int   cur[4][NK];    // running output cursor per (wave's i, k)
    const int blk = blockIdx.x;
    const int m   = blk >> 7;
    const int ig  = blk & 127;
    const int t   = threadIdx.x;
    const int w   = t >> 6;
    const int lane = t & 63;
    const int i   = ig * 4 + w;

    const float* cm = coords + (size_t)m * NAT * 3;
    for (int q = t; q < NAT * 3; q += 256) {
        int a = q / 3, c = q - a * 3;
        float v = cm[q];
        r4[a * 4 + c] = v;
        w4[a * 4 + c] = wrap1(v);
    }
    // load 432 chunk totals (pad to 512 with zeros)
    {
        int v0 = (t < NMOL * NK) ? sums[t] : 0;
        int t2 = t + 256;
        int v1 = (t2 < NMOL * NK) ? sums[t2] : 0;
        sbuf[t] = v0;
        sbuf[t2] = v1;
    }
    __syncthreads();
    // Hillis-Steele inclusive scan over 512 (each thread owns 2 slots)
    for (int d = 1; d < 512; d <<= 1) {
        int a0 = (t >= d) ? sbuf[t - d] : 0;
        int t2 = t + 256;
        int a1 = sbuf[t2 - d];
        __syncthreads();
        sbuf[t]  += a0;
        sbuf[t2] += a1;
        __syncthreads();
    }
    if (t < 4 * NK) {
        int ww = t / NK, k = t % NK;
        int c  = m * NK + k;
        int gbase = (c == 0) ? 0 : sbuf[c - 1];
        cur[ww][k] = cnt[c * NAT + (ig * 4 + ww)] + gbase;
    }
    __syncthreads();

    const float wx = w4[i * 4 + 0];
    const float wy = w4[i * 4 + 1];
    const float wz = w4[i * 4 + 2];
    const float rx = r4[i * 4 + 0];
    const float ry = r4[i * 4 + 1];
    const float rz = r4[i * 4 + 2];
    const float4* w4p = reinterpret_cast<const float4*>(w4);
    const float4* r4p = reinterpret_cast<const float4*>(r4);
    const int pf = m * NAT + i;
    const unsigned long long ltmask =
        (lane == 0) ? 0ull : (~0ull >> (64 - lane));

    for (int it = 0; it < NAT / 64; ++it) {
        const int j = it * 64 + lane;
        float4 wj = w4p[j];
        float dx = __fsub_rn(wx, wj.x);
        float dy = __fsub_rn(wy, wj.y);
        float dz = __fsub_rn(wz, wj.z);
        int ox, oy, oz; float cx, cy, cz;
        bool hit = probe(dx, dy, dz, ox, oy, oz, cx, cy, cz) && (j != i);
        int kk = hit ? ((ox + 1) * 9 + (oy + 1) * 3 + (oz + 1)) : 0;

        // match-any over 5-bit kk among hitting lanes
        unsigned long long grp = __ballot(hit);
        #pragma unroll
        for (int b = 0; b < 5; ++b) {
            unsigned long long bm = __ballot((kk >> b) & 1);
            grp &= ((kk >> b) & 1) ? bm : ~bm;
        }
        int leader = hit ? (__ffsll((unsigned long long)grp) - 1) : 0;
        int cntg   = __popcll(grp);
        int rank   = __popcll(grp & ltmask);

        int base = 0;
        if (hit && lane == leader)
            base = atomicAdd(&cur[w][kk], cntg);   // ds_add_rtn
        base = __shfl(base, leader, 64);           // broadcast from group leader

        if (hit) {
            int p = base + rank;
            if (p < P) {
                float4 rj = r4p[j];
                float px = __fadd_rn(__fsub_rn(rx, rj.x), cx);
                float py = __fadd_rn(__fsub_rn(ry, rj.y), cy);
                float pz = __fadd_rn(__fsub_rn(rz, rj.z), cz);
                float ss = __fadd_rn(__fadd_rn(__fmul_rn(px, px), __fmul_rn(py, py)),
                                     __fmul_rn(pz, pz));
                out[p]                 = __fsqrt_rn(ss);        // distflat2
                out[P + p]             = (float)pf;             // pair_first
                out[2 * P + p]         = (float)(m * NAT + j);  // pair_second
                out[3 * P + 3 * p + 0] = px;                    // paircoord
                out[3 * P + 3 * p + 1] = py;
                out[3 * P + 3 * p + 2] = pz;
                out[6 * P + 3 * p + 0] = (float)ox;             // offsets
                out[6 * P + 3 * p + 1] = (float)oy;
                out[6 * P + 3 * p + 2] = (float)oz;
                out[9 * P + p]         = (float)kk;             // offset_index (n_images=1)
            }
        }
    }
}

extern "C" void kernel_launch(void* const* d_in, const int* in_sizes, int n_in,
                              void* d_out, int out_size, void* d_ws, size_t ws_size,
                              hipStream_t stream) {
    const float* coords = (const float*)d_in[0];
    int* cnt  = (int*)d_ws;               // NMOL*NK*NAT ints
    int* sums = cnt + NMOL * NK * NAT;    // NMOL*NK ints (raw chunk totals)
    float* out = (float*)d_out;
    const int P = out_size / 10;

    hipLaunchKernelGGL(pass_count, dim3(NMOL * NAT / 4), dim3(256), 0, stream, coords, cnt);
    hipLaunchKernelGGL(scan_chunk, dim3(NMOL * NK), dim3(512), 0, stream, cnt, sums);
    hipLaunchKernelGGL(pass_emit, dim3(NMOL * NAT / 4), dim3(256), 0, stream,
                       coords, cnt, sums, out, P);
}